// Round 1
// baseline (456.118 us; speedup 1.0000x reference)
//
#include <hip/hip_runtime.h>

// Problem constants
#define N_    8
#define TP_   2048
#define E_    4096
#define S_    8
#define C_    64
#define T_    16384      // TP_*S_
#define TS_   131072     // T_*S_
#define OUTW  17         // V+1
#define OUT_ELEMS 17825792  // N_*TS_*OUTW
#define F4_PER_N 557056     // 16384 rows * 34 float4 per row
#define F4_TOTAL 4456448    // OUT_ELEMS/4
#define KSTEPS 128          // E_ / 32
#define GEMM_BLOCKS 512
#define FILL_BLOCKS 4352    // F4_TOTAL / 1024 (4 float4 per thread)
#define MPREP_BLOCKS 256    // one per 16-k half-kstep

typedef __attribute__((ext_vector_type(8))) short short8;
typedef __attribute__((ext_vector_type(4))) float float4v;

static __device__ __forceinline__ unsigned short f2bf(float f) {
    unsigned int u = __builtin_bit_cast(unsigned int, f);
    u += 0x7FFFu + ((u >> 16) & 1u);   // round-to-nearest-even
    return (unsigned short)(u >> 16);
}
static __device__ __forceinline__ float bf2f(unsigned short h) {
    return __builtin_bit_cast(float, (unsigned int)h << 16);
}

// ---------------------------------------------------------------------------
// prep_compact: blocks 0..63 = compact (unchanged proven logic);
// blocks 64..319 = M precompute.
//   M[s][e][s2] = sum_c W1[e,c,s]*W2[c,s2]  -> contracts away the C=64 dim.
//   Stored bf16 hi/lo split, pre-arranged in MFMA B-fragment order:
//   Mfrag[((s*128 + kstep)*64 + lane)*8 + j] = M[kstep*32+(lane>>4)*8+j][lane&15]
//   (cols 8..15 zero).  Block = (kstep, half): stages 16 contiguous W1 rows
//   (32 KB LDS, fully coalesced) and computes the matching q-pairs.
// ---------------------------------------------------------------------------
__global__ __launch_bounds__(256) void prep_compact_kernel(
    const float* __restrict__ W1, const float* __restrict__ b1,
    const float* __restrict__ W2, const float* __restrict__ b2,
    const int* __restrict__ value, const int* __restrict__ depth,
    unsigned short* __restrict__ Mhi, unsigned short* __restrict__ Mlo,
    float* __restrict__ K2,
    int* __restrict__ cnt_ns, int* __restrict__ cnt_total,
    int* __restrict__ tile_counter, int* __restrict__ tiles,
    int* __restrict__ sel_tp, int* __restrict__ sel_j)
{
    const int tid = threadIdx.x;
    const int b   = blockIdx.x;

    if (b < 64) {
        // ---------------- compact ----------------
        __shared__ int idx_sh;
        __shared__ unsigned int wsum[4];
        const int g = b;                   // n*8 + s
        const int n = g >> 3;
        const int s = g & 7;
        const int lane = tid & 63;
        const int wv   = tid >> 6;

        const int* d = depth + (size_t)n * T_;
        if (tid < 64) {                    // wave 0: 64-ary search, 3 rounds
            int maxv = d[T_ - 1];
            int lower = 0, upper = T_ - 1;
            for (int rnd = 0; rnd < 3; ++rnd) {
                int span = upper - lower;
                int step = (span + 63) >> 6;
                if (step < 1) step = 1;
                int p = lower + lane * step;
                if (p > upper) p = upper;
                unsigned long long bb = __ballot(d[p] == maxv);
                int f = __ffsll((long long)bb) - 1;
                int nu = lower + f * step; if (nu > upper) nu = upper;
                int nl = (f == 0) ? lower : lower + (f - 1) * step + 1;
                if (nl > nu) nl = nu;
                lower = nl; upper = nu;
            }
            if (lane == 0) idx_sh = lower;
        }
        __syncthreads();
        const int idx = idx_sh;
        const int4* val4 = (const int4*)(value + (size_t)n * T_);

        const int b4 = tid * 16;
        unsigned int packed = 0;           // (any-count << 16) | s-residue count
        for (int i = 0; i < 16; ++i) {
            int4 v = val4[b4 + i];
            int t = (b4 + i) * 4;
            if (t + 0 < idx && v.x == 2) { packed += 0x10000u; if (((t + 0) & 7) == s) packed += 1u; }
            if (t + 1 < idx && v.y == 2) { packed += 0x10000u; if (((t + 1) & 7) == s) packed += 1u; }
            if (t + 2 < idx && v.z == 2) { packed += 0x10000u; if (((t + 2) & 7) == s) packed += 1u; }
            if (t + 3 < idx && v.w == 2) { packed += 0x10000u; if (((t + 3) & 7) == s) packed += 1u; }
        }
        unsigned int inc = packed;
#pragma unroll
        for (int off = 1; off < 64; off <<= 1) {
            unsigned int u = __shfl_up((int)inc, off, 64);
            if (lane >= off) inc += u;
        }
        if (lane == 63) wsum[wv] = inc;
        __syncthreads();
        unsigned int woff = 0;
        for (int ww = 0; ww < wv; ++ww) woff += wsum[ww];
        unsigned int excl = woff + inc - packed;
        int any_rank = (int)(excl >> 16);
        int s_rank   = (int)(excl & 0xFFFFu);
        for (int i = 0; i < 16; ++i) {
            int4 v = val4[b4 + i];
            int vv[4] = { v.x, v.y, v.z, v.w };
            int t = (b4 + i) * 4;
#pragma unroll
            for (int e = 0; e < 4; ++e) {
                int tt = t + e;
                if (tt < idx && vv[e] == 2) {
                    if ((tt & 7) == s) {
                        sel_tp[g * 2048 + s_rank] = tt >> 3;
                        sel_j [g * 2048 + s_rank] = any_rank;
                        ++s_rank;
                    }
                    ++any_rank;
                }
            }
        }
        if (tid == 255) {
            unsigned int tot = woff + inc;
            int cnt = (int)(tot & 0xFFFFu);
            cnt_ns[g] = cnt;
            if (s == 0) cnt_total[n] = (int)(tot >> 16);
            int ntl = (cnt + 63) >> 6;
            int base = atomicAdd(tile_counter, ntl);
            for (int i = 0; i < ntl; ++i) tiles[base + i] = (g << 8) | i;
        }
        return;
    }

    // ---------------- M precompute ----------------
    __shared__ float W1t[16 * 512];   // 32 KB: 16 contiguous W1 rows (e-major)
    __shared__ float W2s[512];

    if (b == 64 && tid < 8) {
        int s2 = tid;
        float acc = b2[0];
        for (int c = 0; c < C_; ++c) acc += b1[c] * W2[c * S_ + s2];
        K2[s2] = acc;
    }

    const int kk    = b - 64;          // 0..255
    const int kstep = kk >> 1;         // 0..127
    const int h     = kk & 1;          // which 16-k half of the 32-k step
    const int k0    = kstep * 32 + h * 16;

    for (int i = tid; i < 512; i += 256) W2s[i] = W2[i];
    {
        const float4* src = (const float4*)(W1 + (size_t)k0 * 512);
        float4* dst = (float4*)W1t;
        for (int i = tid; i < 16 * 128; i += 256) dst[i] = src[i];
    }
    __syncthreads();

    const int s    = tid >> 5;         // 0..7
    const int lsub = tid & 31;
    const int lane = h * 32 + lsub;    // fragment lane 0..63
    const int qq   = lsub >> 4;        // local row-group within the 16 k's
    const int s2   = lane & 15;        // output col (valid if < 8)

    float accj[8] = {0.f,0.f,0.f,0.f,0.f,0.f,0.f,0.f};
    if (s2 < 8) {
        for (int c = 0; c < C_; ++c) {
            float w2 = W2s[c * 8 + s2];
            int base = c * 8 + s;
#pragma unroll
            for (int j = 0; j < 8; ++j)
                accj[j] += W1t[(qq * 8 + j) * 512 + base] * w2;
        }
    }
    size_t o = ((size_t)(s * KSTEPS + kstep) * 64 + lane) * 8;
#pragma unroll
    for (int j = 0; j < 8; ++j) {
        unsigned short hi = f2bf(accj[j]);
        unsigned short lo = f2bf(accj[j] - bf2f(hi));
        Mhi[o + j] = hi;
        Mlo[o + j] = lo;
    }
}

// ---------------------------------------------------------------------------
// main: blocks < GEMM_BLOCKS do the gathered rows x M GEMM (M=64-row tiles,
// N=8 via 16x16x32 MFMA with zeroed cols 8..15, K=4096).  The k-loop is
// BARRIER-FREE: A-fragments load straight from gathered x rows (the
// lane->(row, k=q*8+j) fragment layout matches two float4 loads exactly),
// B-fragments stream from pre-fragment-ordered Mhi/Mlo in global (L1-hot,
// identical addresses across all 4 waves).  hi/lo split keeps M at ~f32
// precision, so only x is bf16-rounded (error <= previous version).
// Blocks >= GEMM_BLOCKS perform the fill (disjoint rows: j >= cnt_total).
// ---------------------------------------------------------------------------
__global__ __launch_bounds__(256) void main_kernel(
    const float* __restrict__ x,
    const unsigned short* __restrict__ Mhi, const unsigned short* __restrict__ Mlo,
    const int* __restrict__ tile_counter, const int* __restrict__ tiles,
    const int* __restrict__ cnt_ns, const int* __restrict__ sel_tp,
    const int* __restrict__ sel_j, const float* __restrict__ K2,
    const float* __restrict__ W3, const float* __restrict__ b2,
    const int* __restrict__ cnt_total, float* __restrict__ out)
{
    const int tid = threadIdx.x;

    if (blockIdx.x >= GEMM_BLOCKS) {
        // ---------------- fill ----------------
        __shared__ float pat[136];
        if (tid < 136) pat[tid] = b2[0] * W3[tid % OUTW];
        __syncthreads();
        const int fb = blockIdx.x - GEMM_BLOCKS;
#pragma unroll
        for (int it = 0; it < 4; ++it) {
            int i4 = fb * 1024 + it * 256 + tid;   // < F4_TOTAL exactly
            int n   = i4 / F4_PER_N;
            int rem = i4 - n * F4_PER_N;
            int j   = rem / 34;
            if (j >= cnt_total[n]) {
                int o = (rem - j * 34) * 4;
                float4 v = { pat[o], pat[o + 1], pat[o + 2], pat[o + 3] };
                *(float4*)&out[(size_t)i4 * 4] = v;
            }
        }
        return;
    }

    // ---------------- GEMM ----------------
    __shared__ int tp_l[64], j_l[64];
    __shared__ float y2s[64][8];
    __shared__ float W3s[OUTW];
    __shared__ float K2s[S_];

    if (tid < OUTW) W3s[tid] = W3[tid];
    if (tid < S_)   K2s[tid] = K2[tid];

    const int ntile = *tile_counter;
    const int lane = tid & 63;
    const int w    = tid >> 6;        // wave id: rows [w*16, w*16+16)
    const int m    = lane & 15;       // A row within wave / D col
    const int q    = lane >> 4;       // k sub-slice (q*8..q*8+8) within 32-k step

    for (int ti = blockIdx.x; ti < ntile; ti += GEMM_BLOCKS) {
        const int ent = tiles[ti];
        const int g = ent >> 8;
        const int n = g >> 3;
        const int s = g & 7;
        const int m0 = (ent & 255) * 64;
        const int rows = min(64, cnt_ns[g] - m0);

        __syncthreads();   // previous tile's epilogue reads of tp_l/j_l/y2s done
        if (tid < 64) {
            int tp = 0, j = 0;
            if (tid < rows) {
                tp = sel_tp[g * 2048 + m0 + tid];
                j  = sel_j [g * 2048 + m0 + tid];
            }
            tp_l[tid] = tp;
            j_l[tid]  = j;
        }
        __syncthreads();

        const float* arow = x + ((size_t)n * TP_ + tp_l[w * 16 + m]) * E_ + q * 8;
        const unsigned short* bh = Mhi + ((size_t)s * KSTEPS * 64 + lane) * 8;
        const unsigned short* bl = Mlo + ((size_t)s * KSTEPS * 64 + lane) * 8;

        float4v acc = {0.f, 0.f, 0.f, 0.f};

        // 2-step register prefetch, named sets (compile-time parity)
        float4 A00 = *(const float4*)(arow);
        float4 A01 = *(const float4*)(arow + 4);
        short8 Bh0 = *(const short8*)(bh);
        short8 Bl0 = *(const short8*)(bl);
        float4 A10 = *(const float4*)(arow + 32);
        float4 A11 = *(const float4*)(arow + 36);
        short8 Bh1 = *(const short8*)(bh + 512);
        short8 Bl1 = *(const short8*)(bl + 512);

#define STEP(P, A0, A1, BH, BL)                                                \
        {                                                                      \
            short8 av;                                                         \
            av[0] = (short)f2bf(A0.x); av[1] = (short)f2bf(A0.y);              \
            av[2] = (short)f2bf(A0.z); av[3] = (short)f2bf(A0.w);              \
            av[4] = (short)f2bf(A1.x); av[5] = (short)f2bf(A1.y);              \
            av[6] = (short)f2bf(A1.z); av[7] = (short)f2bf(A1.w);              \
            short8 bhc = BH, blc = BL;                                         \
            if (ks + 2 + P < KSTEPS) {                                         \
                const float* ap = arow + (size_t)(ks + 2 + P) * 32;            \
                A0 = *(const float4*)(ap);                                     \
                A1 = *(const float4*)(ap + 4);                                 \
                BH = *(const short8*)(bh + (size_t)(ks + 2 + P) * 512);        \
                BL = *(const short8*)(bl + (size_t)(ks + 2 + P) * 512);        \
            }                                                                  \
            acc = __builtin_amdgcn_mfma_f32_16x16x32_bf16(av, bhc, acc, 0, 0, 0); \
            acc = __builtin_amdgcn_mfma_f32_16x16x32_bf16(av, blc, acc, 0, 0, 0); \
        }

        for (int ks = 0; ks < KSTEPS; ks += 2) {
            STEP(0, A00, A01, Bh0, Bl0)
            STEP(1, A10, A11, Bh1, Bl1)
        }
#undef STEP

        // D layout: row = q*4+rr (within wave's 16), col = lane&15; cols 8..15
        // are zero (zeroed B fragment slots) and ignored.
        if (m < 8) {
#pragma unroll
            for (int rr = 0; rr < 4; ++rr)
                y2s[w * 16 + q * 4 + rr][m] = acc[rr] + K2s[m];
        }
        __syncthreads();

        // coalesced writes: each output row is 136 consecutive floats = 34 f4
        for (int task = tid; task < 64 * 34; task += 256) {
            int row = task / 34;
            int f   = task - row * 34;
            if (row < rows) {
                float4 v;
                float* vp = (float*)&v;
#pragma unroll
                for (int e = 0; e < 4; ++e) {
                    int idx = f * 4 + e;
                    int s2  = (idx * 241) >> 12;   // idx/17 for idx<136
                    int vi  = idx - s2 * OUTW;
                    vp[e] = y2s[row][s2] * W3s[vi];
                }
                *(float4*)&out[((size_t)n * TS_ + (size_t)j_l[row] * S_) * OUTW + f * 4] = v;
            }
        }
    }
}

// ---------------------------------------------------------------------------
extern "C" void kernel_launch(void* const* d_in, const int* in_sizes, int n_in,
                              void* d_out, int out_size, void* d_ws, size_t ws_size,
                              hipStream_t stream) {
    const float* x     = (const float*)d_in[0];
    const int*   value = (const int*)d_in[1];
    const int*   depth = (const int*)d_in[2];
    // d_in[3] = pos (unused by reference)
    const float* W1    = (const float*)d_in[4];
    const float* b1    = (const float*)d_in[5];
    const float* W2    = (const float*)d_in[6];
    const float* b2    = (const float*)d_in[7];
    const float* W3    = (const float*)d_in[8];
    float* out = (float*)d_out;

    // workspace layout (~3.2 MB)
    unsigned short* Mhi = (unsigned short*)d_ws;            // 8*128*64*8 = 1 MB
    unsigned short* Mlo = Mhi + 8 * KSTEPS * 64 * 8;        // 1 MB
    float* K2          = (float*)(Mlo + 8 * KSTEPS * 64 * 8);  // 8
    int* tile_counter  = (int*)(K2 + 8);                    // 1
    int* cnt_ns        = tile_counter + 1;                  // 64
    int* cnt_total     = cnt_ns + 64;                       // 8
    int* tiles         = cnt_total + 8;                     // 2048 max
    int* sel_tp        = tiles + 2048;                      // 64*2048
    int* sel_j         = sel_tp + 64 * 2048;                // 64*2048

    hipMemsetAsync(tile_counter, 0, sizeof(int), stream);

    prep_compact_kernel<<<64 + MPREP_BLOCKS, 256, 0, stream>>>(
        W1, b1, W2, b2, value, depth, Mhi, Mlo, K2,
        cnt_ns, cnt_total, tile_counter, tiles, sel_tp, sel_j);

    main_kernel<<<GEMM_BLOCKS + FILL_BLOCKS, 256, 0, stream>>>(
        x, Mhi, Mlo, tile_counter, tiles, cnt_ns, sel_tp, sel_j,
        K2, W3, b2, cnt_total, out);
}